// Round 2
// baseline (17652.365 us; speedup 1.0000x reference)
//
#include <hip/hip_runtime.h>
#include <hip/hip_bf16.h>
#include <stdint.h>

// B=64, T=512, D=128, H=512, C=256
#define SMEM_BYTES 148480

using short8 = __attribute__((ext_vector_type(8))) short;
using f32x4  = __attribute__((ext_vector_type(4))) float;

// ---------------- workspace layout (bytes) ----------------
#define OXBF 0u
#define OYBF 8388608u
#define OWE0 16777216u               // cell0 enc blob: 32 ub * 81920
#define OWD0 (OWE0 + 2621440u)
#define OWE1 (OWD0 + 2621440u)       // cell1 enc blob: 32 ub * 131072
#define OWD1 (OWE1 + 4194304u)
#define OWC1 (OWD1 + 4194304u)       // 16 * 16KB
#define OWC2 (OWC1 + 262144u)        // 8 * 8KB
#define OH0  (OWC2 + 65536u)         // h0 ring [8][64][512] bf16 = 512KB
#define OH1  (OH0 + 524288u)
#define OHP  (OH1 + 524288u)         // hid ring [8][64][256] bf16 = 256KB
#define OFLG (OHP + 262144u)         // flags: FC0(64*64B) FC1(64*64B) FH(16*64B) FL(8*64B)
#define OFC0 (OFLG)
#define OFC1 (OFLG + 4096u)
#define OFH  (OFLG + 8192u)
#define OFL  (OFLG + 9216u)

// ---------------- helpers ----------------
static __device__ __forceinline__ unsigned short f2bf(float f){
  union { float f; unsigned u; } v; v.f = f;
  unsigned r = v.u + 0x7FFFu + ((v.u >> 16) & 1u);
  return (unsigned short)(r >> 16);
}
static __device__ __forceinline__ float sigm(float x){ return 1.f/(1.f+__expf(-x)); }
static __device__ __forceinline__ float tanh_(float x){ return 1.f - 2.f/(__expf(2.f*x)+1.f); }

// ---------------- prep kernels ----------------
__global__ void k_init(float* __restrict__ out, uint8_t* __restrict__ ws){
  int i = blockIdx.x*blockDim.x + threadIdx.x;
  int ns = gridDim.x*blockDim.x;
  uint32_t* z = (uint32_t*)(ws + OH0);
  const int n32 = (int)((OFLG + 16384u - OH0)/4u);   // rings + flags
  for (int k=i; k<n32; k+=ns) z[k] = 0u;
  for (int k=i; k<64*128; k+=ns) out[(size_t)(k>>7)*(512*128) + (k&127)] = 0.f;
}

__global__ void k_cvt(const float* __restrict__ x, const float* __restrict__ y,
                      uint8_t* __restrict__ ws){
  unsigned short* xb = (unsigned short*)(ws + OXBF);
  unsigned short* yb = (unsigned short*)(ws + OYBF);
  const int n = 64*512*128;
  int i = blockIdx.x*blockDim.x + threadIdx.x, ns = gridDim.x*blockDim.x;
  for (int k=i; k<n; k+=ns){ xb[k] = f2bf(x[k]); yb[k] = f2bf(y[k]); }
}

// gate-cell weight swizzle: frag idx = ((((ub*4 + w)*NKK + kk)*4 + g)*64 + lane)*8 + j
// mode 1 (cell0): k = kk==0 ? w*32+off : 128 + w*128 + (kk-1)*32 + off
// mode 0 (cell1): k = w*KC + kk*32 + off
__global__ void k_swzgate(const float* __restrict__ Wih, const float* __restrict__ Whh,
                          uint8_t* __restrict__ ws, size_t dstOff, int Kin, int KC, int NKK, int mode){
  unsigned short* dst = (unsigned short*)(ws + dstOff);
  const int total = 2048 * (KC*4);
  int i = blockIdx.x*blockDim.x + threadIdx.x, ns = gridDim.x*blockDim.x;
  for (int idx=i; idx<total; idx+=ns){
    int j = idx & 7;
    int lane = (idx >> 3) & 63;
    int t = idx >> 9;
    int g = t & 3; t >>= 2;
    int kk = t % NKK; t /= NKK;
    int w = t & 3; int ub = t >> 2;
    int off = ((lane>>4)<<3) + j;
    int k = mode ? (kk==0 ? w*32 + off : 128 + w*128 + (kk-1)*32 + off)
                 : (w*KC + kk*32 + off);
    int u = ub*16 + (lane&15);
    int row = g*512 + u;
    float v = (k < Kin) ? Wih[(size_t)row*Kin + k] : Whh[(size_t)row*512 + (k-Kin)];
    dst[idx] = f2bf(v);
  }
}

// clf weight swizzle: frag idx = (((wg*4 + w)*NKK + kk)*64 + lane)*8 + j ; k = w*Kw + kk*32 + off
__global__ void k_swzclf(const float* __restrict__ W, uint8_t* __restrict__ ws,
                         size_t dstOff, int nwgs, int Kw, int Ktot){
  unsigned short* dst = (unsigned short*)(ws + dstOff);
  const int NKK = Kw/32;
  const int total = nwgs*4*NKK*64*8;
  int i = blockIdx.x*blockDim.x + threadIdx.x, ns = gridDim.x*blockDim.x;
  for (int idx=i; idx<total; idx+=ns){
    int j = idx & 7;
    int lane = (idx >> 3) & 63;
    int t = idx >> 9;
    int kk = t % NKK; t /= NKK;
    int w = t & 3; int wg = t >> 2;
    int k = w*Kw + kk*32 + ((lane>>4)<<3) + j;
    int col = wg*16 + (lane&15);
    dst[idx] = f2bf(W[(size_t)col*Ktot + k]);
  }
}

// ---------------- persistent dataflow kernel ----------------
// roles: wg 0..63 cell0 (bt=wg>>5, ub=wg&31); 64..127 cell1; 128..143 hid; 144..151 log
__launch_bounds__(256, 1)
__global__ void k_seq(uint8_t* __restrict__ ws,
                      const float* __restrict__ eb0, const float* __restrict__ eb1,
                      const float* __restrict__ db0, const float* __restrict__ db1,
                      const float* __restrict__ cb1, const float* __restrict__ cb2,
                      float* __restrict__ out){
  __shared__ uint8_t smem[SMEM_BYTES];
  const int wg = blockIdx.x, tid = threadIdx.x;
  const int w = tid>>6, l = tid&63, lr = l&15, lg = l>>4;

  const unsigned short* xb = (const unsigned short*)(ws+OXBF);
  const unsigned short* yb = (const unsigned short*)(ws+OYBF);
  unsigned short* h0r = (unsigned short*)(ws+OH0);
  unsigned short* h1r = (unsigned short*)(ws+OH1);
  unsigned short* hpr = (unsigned short*)(ws+OHP);

  short8* BL = (short8*)smem;
  float*  P0 = (float*)(smem + 131072);   // padded partials: cell 32*68, clf 64*20
  float*  P1 = (float*)(smem + 139776);

  auto loadB = [&](size_t srcOff, int bytes){
    const uint4* s = (const uint4*)(ws + srcOff);
    uint4* d = (uint4*)smem;
    for (int i = tid; i < bytes/16; i += 256) d[i] = s[i];
  };
  auto pollge = [&](uint32_t baseOff, int n, int tgt, int tb){
    if (tgt > 0 && tid >= tb && tid < tb+n){
      const unsigned* p = (const unsigned*)(ws + baseOff + (size_t)(tid-tb)*64);
      while ((int)__hip_atomic_load(p, __ATOMIC_RELAXED, __HIP_MEMORY_SCOPE_AGENT) < tgt)
        __builtin_amdgcn_s_sleep(1);
    }
  };
  auto setflag = [&](uint32_t slotOff, int val){
    __syncthreads();   // all h stores done (barrier drains vmcnt per wave)
    if (tid == 0)
      __hip_atomic_store((unsigned*)(ws + slotOff), (unsigned)val,
                         __ATOMIC_RELEASE, __HIP_MEMORY_SCOPE_AGENT);
  };

  if (wg < 128){
    // ---------------- LSTM cells ----------------
    const bool isC0 = wg < 64;
    const int cwg = isC0 ? wg : wg-64;
    const int bt = cwg>>5, ub = cwg&31;
    const int u = tid&15, ug = ub*16 + u;
    const int NKK = isC0 ? 5 : 8;
    const int bbytes = isC0 ? 81920 : 131072;
    const uint32_t myflag = (isC0 ? OFC0 : OFC1) + (uint32_t)(bt*32+ub)*64u;

    float be[4], bd[4];
    {
      const float* e = isC0 ? eb0 : eb1;
      const float* d = isC0 ? db0 : db1;
      #pragma unroll
      for (int g=0; g<4; ++g){ be[g] = e[g*512+ug]; bd[g] = d[g*512+ug]; }
    }
    loadB((isC0 ? (size_t)OWE0 : (size_t)OWE1) + (size_t)ub*bbytes, bbytes);
    float cS0 = 0.f, cS1 = 0.f;
    __syncthreads();

    for (int t = 0; t < 1023; ++t){
      if (t == 512){
        __syncthreads();
        loadB((isC0 ? (size_t)OWD0 : (size_t)OWD1) + (size_t)ub*bbytes, bbytes);
      }
      if (isC0){
        pollge(OFC0 + bt*2048u, 32, t, 0);        // h0(t-1) ready (own group)
        pollge(OFC1 + bt*2048u, 32, t-7, 32);     // WAR: c1 done reading h0(t-8)
      } else {
        pollge(OFC0 + bt*2048u, 32, t+1, 0);      // h0(t) ready
        pollge(OFC1 + bt*2048u, 32, t, 32);       // h1(t-1) ready (own group)
        pollge(OFH, 16, t-519, 64);               // WAR: hid done reading h1(t-8)
      }
      __threadfence();
      __syncthreads();

      const int slotW = t&7, slotR = (t+7)&7;
      f32x4 acc[2][4];
      #pragma unroll
      for (int m=0;m<2;++m)
        #pragma unroll
        for (int g=0;g<4;++g) acc[m][g] = (f32x4){0.f,0.f,0.f,0.f};

      if (isC0){
        const unsigned short* xs = (t<512) ? xb : yb;
        const int tt = (t<512) ? t : t-512;
        for (int kk=0; kk<5; ++kk){
          short8 a[2];
          #pragma unroll
          for (int m=0;m<2;++m){
            const int b = bt*32 + m*16 + lr;
            const unsigned short* ap = (kk==0)
              ? xs + ((size_t)b*512 + tt)*128 + w*32 + (lg<<3)
              : h0r + ((size_t)slotR*64 + b)*512 + w*128 + (kk-1)*32 + (lg<<3);
            a[m] = *(const short8*)ap;
          }
          #pragma unroll
          for (int g=0;g<4;++g){
            short8 bf = BL[((w*5+kk)*4+g)*64 + l];
            acc[0][g] = __builtin_amdgcn_mfma_f32_16x16x32_bf16(a[0], bf, acc[0][g],0,0,0);
            acc[1][g] = __builtin_amdgcn_mfma_f32_16x16x32_bf16(a[1], bf, acc[1][g],0,0,0);
          }
        }
      } else {
        for (int kk=0; kk<8; ++kk){
          const int k0 = w*256 + kk*32;
          short8 a[2];
          #pragma unroll
          for (int m=0;m<2;++m){
            const int b = bt*32 + m*16 + lr;
            const unsigned short* ap = (k0 < 512)
              ? h0r + ((size_t)slotW*64 + b)*512 + k0 + (lg<<3)
              : h1r + ((size_t)slotR*64 + b)*512 + (k0-512) + (lg<<3);
            a[m] = *(const short8*)ap;
          }
          #pragma unroll
          for (int g=0;g<4;++g){
            short8 bf = BL[((w*8+kk)*4+g)*64 + l];
            acc[0][g] = __builtin_amdgcn_mfma_f32_16x16x32_bf16(a[0], bf, acc[0][g],0,0,0);
            acc[1][g] = __builtin_amdgcn_mfma_f32_16x16x32_bf16(a[1], bf, acc[1][g],0,0,0);
          }
        }
      }

      // 2-round split-K reduce: w0->P0, w1->P1; barrier; w2->P0+, w3->P1+
      {
        float* P = (w&1) ? P1 : P0;
        if (w < 2){
          #pragma unroll
          for (int m=0;m<2;++m)
            #pragma unroll
            for (int g=0;g<4;++g)
              #pragma unroll
              for (int r=0;r<4;++r)
                P[(m*16 + (lg<<2) + r)*68 + g*16 + lr] = acc[m][g][r];
        }
        __syncthreads();
        if (w >= 2){
          #pragma unroll
          for (int m=0;m<2;++m)
            #pragma unroll
            for (int g=0;g<4;++g)
              #pragma unroll
              for (int r=0;r<4;++r)
                P[(m*16 + (lg<<2) + r)*68 + g*16 + lr] += acc[m][g][r];
        }
        __syncthreads();
      }

      // activation epilogue: 2 outputs/thread (rows tid>>4 and +16, unit u)
      const float* bias = (t<512) ? be : bd;
      unsigned short* hout = isC0 ? h0r : h1r;
      #pragma unroll
      for (int s=0;s<2;++s){
        const int row = (tid>>4) + s*16;
        const int pi = row*68 + u;
        float gi = P0[pi]      + P1[pi]      + bias[0];
        float gf = P0[pi+16]   + P1[pi+16]   + bias[1];
        float gg = P0[pi+32]   + P1[pi+32]   + bias[2];
        float go = P0[pi+48]   + P1[pi+48]   + bias[3];
        float cprev = s ? cS1 : cS0;
        float c = sigm(gf)*cprev + sigm(gi)*tanh_(gg);
        if (s) cS1 = c; else cS0 = c;
        float h = sigm(go)*tanh_(c);
        hout[((size_t)slotW*64 + (bt*32+row))*512 + ug] = f2bf(h);
      }
      setflag(myflag, t+1);
    }
  } else if (wg < 144){
    // ---------------- clf hidden: relu(h1 @ W1^T + b1) ----------------
    const int hwg = wg - 128;
    const int u = tid&15, col = hwg*16 + u;
    const float bc = cb1[col];
    loadB((size_t)OWC1 + (size_t)hwg*16384, 16384);
    __syncthreads();
    for (int t2 = 0; t2 < 511; ++t2){
      pollge(OFC1, 64, 513+t2, 0);               // c1 (both halves) done step 512+t2
      pollge(OFL, 8, t2-7, 64);                  // WAR: log done reading hid(t2-8)
      __threadfence();
      __syncthreads();
      const int slot = (512+t2)&7, slw = t2&7;
      f32x4 ha[4];
      #pragma unroll
      for (int m=0;m<4;++m) ha[m] = (f32x4){0.f,0.f,0.f,0.f};
      for (int kk=0; kk<4; ++kk){
        short8 bf = BL[(w*4+kk)*64 + l];
        #pragma unroll
        for (int m=0;m<4;++m){
          const unsigned short* ap = h1r + ((size_t)slot*64 + m*16+lr)*512 + w*128 + kk*32 + (lg<<3);
          short8 a = *(const short8*)ap;
          ha[m] = __builtin_amdgcn_mfma_f32_16x16x32_bf16(a, bf, ha[m],0,0,0);
        }
      }
      {
        float* P = (w&1) ? P1 : P0;
        if (w < 2){
          #pragma unroll
          for (int m=0;m<4;++m)
            #pragma unroll
            for (int r=0;r<4;++r)
              P[(m*16 + (lg<<2) + r)*20 + lr] = ha[m][r];
        }
        __syncthreads();
        if (w >= 2){
          #pragma unroll
          for (int m=0;m<4;++m)
            #pragma unroll
            for (int r=0;r<4;++r)
              P[(m*16 + (lg<<2) + r)*20 + lr] += ha[m][r];
        }
        __syncthreads();
      }
      #pragma unroll
      for (int s=0;s<4;++s){
        const int row = (tid>>4) + s*16;
        float v = P0[row*20+u] + P1[row*20+u] + bc;
        v = fmaxf(v, 0.f);
        hpr[((size_t)slw*64 + row)*256 + col] = f2bf(v);
      }
      setflag(OFH + (uint32_t)hwg*64u, t2+1);
    }
  } else if (wg < 152){
    // ---------------- clf logits: hid @ W2^T + b2 -> out ----------------
    const int lwg = wg - 144;
    const int u = tid&15, col = lwg*16 + u;
    const float bc = cb2[col];
    loadB((size_t)OWC2 + (size_t)lwg*8192, 8192);
    __syncthreads();
    for (int t3 = 0; t3 < 511; ++t3){
      pollge(OFH, 16, t3+1, 0);
      __threadfence();
      __syncthreads();
      const int slot = t3&7;
      f32x4 la[4];
      #pragma unroll
      for (int m=0;m<4;++m) la[m] = (f32x4){0.f,0.f,0.f,0.f};
      for (int kk=0; kk<2; ++kk){
        short8 bf = BL[(w*2+kk)*64 + l];
        #pragma unroll
        for (int m=0;m<4;++m){
          const unsigned short* ap = hpr + ((size_t)slot*64 + m*16+lr)*256 + w*64 + kk*32 + (lg<<3);
          short8 a = *(const short8*)ap;
          la[m] = __builtin_amdgcn_mfma_f32_16x16x32_bf16(a, bf, la[m],0,0,0);
        }
      }
      {
        float* P = (w&1) ? P1 : P0;
        if (w < 2){
          #pragma unroll
          for (int m=0;m<4;++m)
            #pragma unroll
            for (int r=0;r<4;++r)
              P[(m*16 + (lg<<2) + r)*20 + lr] = la[m][r];
        }
        __syncthreads();
        if (w >= 2){
          #pragma unroll
          for (int m=0;m<4;++m)
            #pragma unroll
            for (int r=0;r<4;++r)
              P[(m*16 + (lg<<2) + r)*20 + lr] += la[m][r];
        }
        __syncthreads();
      }
      #pragma unroll
      for (int s=0;s<4;++s){
        const int row = (tid>>4) + s*16;
        float v = P0[row*20+u] + P1[row*20+u] + bc;
        out[((size_t)row*512 + (t3+1))*128 + col] = v;
      }
      setflag(OFL + (uint32_t)lwg*64u, t3+1);
    }
  }
}

// ---------------- launch ----------------
extern "C" void kernel_launch(void* const* d_in, const int* in_sizes, int n_in,
                              void* d_out, int out_size, void* d_ws, size_t ws_size,
                              hipStream_t stream){
  const float* x   = (const float*)d_in[0];
  const float* y   = (const float*)d_in[1];
  const float* eW0 = (const float*)d_in[2];
  const float* eU0 = (const float*)d_in[3];
  const float* eb0 = (const float*)d_in[4];
  const float* eW1 = (const float*)d_in[5];
  const float* eU1 = (const float*)d_in[6];
  const float* eb1 = (const float*)d_in[7];
  const float* dW0 = (const float*)d_in[8];
  const float* dU0 = (const float*)d_in[9];
  const float* db0 = (const float*)d_in[10];
  const float* dW1 = (const float*)d_in[11];
  const float* dU1 = (const float*)d_in[12];
  const float* db1 = (const float*)d_in[13];
  const float* cW1 = (const float*)d_in[14];
  const float* cb1 = (const float*)d_in[15];
  const float* cW2 = (const float*)d_in[16];
  const float* cb2 = (const float*)d_in[17];
  float* out = (float*)d_out;
  uint8_t* ws = (uint8_t*)d_ws;
  (void)in_sizes; (void)n_in; (void)out_size; (void)ws_size;

  k_init<<<dim3(256), dim3(256), 0, stream>>>(out, ws);
  k_cvt<<<dim3(2048), dim3(256), 0, stream>>>(x, y, ws);
  k_swzgate<<<dim3(1280), dim3(256), 0, stream>>>(eW0, eU0, ws, (size_t)OWE0, 128, 160, 5, 1);
  k_swzgate<<<dim3(1280), dim3(256), 0, stream>>>(dW0, dU0, ws, (size_t)OWD0, 128, 160, 5, 1);
  k_swzgate<<<dim3(2048), dim3(256), 0, stream>>>(eW1, eU1, ws, (size_t)OWE1, 512, 256, 8, 0);
  k_swzgate<<<dim3(2048), dim3(256), 0, stream>>>(dW1, dU1, ws, (size_t)OWD1, 512, 256, 8, 0);
  k_swzclf<<<dim3(256), dim3(256), 0, stream>>>(cW1, ws, (size_t)OWC1, 16, 128, 512);
  k_swzclf<<<dim3(64),  dim3(256), 0, stream>>>(cW2, ws, (size_t)OWC2, 8, 64, 256);
  k_seq<<<dim3(152), dim3(256), 0, stream>>>(ws, eb0, eb1, db0, db1, cb1, cb2, out);
}

// Round 3
// 5310.285 us; speedup vs baseline: 3.3242x; 3.3242x over previous
//
#include <hip/hip_runtime.h>
#include <hip/hip_bf16.h>
#include <stdint.h>

// B=64, T=512, D=128, H=512, C=256
#define SMEM_BYTES 148480

using short8 = __attribute__((ext_vector_type(8))) short;
using f32x4  = __attribute__((ext_vector_type(4))) float;

// ---------------- workspace layout (bytes) ----------------
#define OXBF 0u
#define OYBF 8388608u
#define OWE0 16777216u               // cell0 enc blob: 32 ub * 81920
#define OWD0 (OWE0 + 2621440u)
#define OWE1 (OWD0 + 2621440u)       // cell1 enc blob: 32 ub * 131072
#define OWD1 (OWE1 + 4194304u)
#define OWC1 (OWD1 + 4194304u)       // 16 * 16KB
#define OWC2 (OWC1 + 262144u)        // 8 * 8KB
#define OH0  (OWC2 + 65536u)         // h0 ring [8][64][512] bf16 = 512KB
#define OH1  (OH0 + 524288u)
#define OHP  (OH1 + 524288u)         // hid ring [8][64][256] bf16 = 256KB
#define OFLG (OHP + 262144u)         // flags: FC0(64*64B) FC1(64*64B) FH(16*64B) FL(8*64B)
#define OFC0 (OFLG)
#define OFC1 (OFLG + 4096u)
#define OFH  (OFLG + 8192u)
#define OFL  (OFLG + 9216u)

// ---------------- helpers ----------------
static __device__ __forceinline__ unsigned short f2bf(float f){
  union { float f; unsigned u; } v; v.f = f;
  unsigned r = v.u + 0x7FFFu + ((v.u >> 16) & 1u);
  return (unsigned short)(r >> 16);
}
static __device__ __forceinline__ float sigm(float x){ return 1.f/(1.f+__expf(-x)); }
static __device__ __forceinline__ float tanh_(float x){ return 1.f - 2.f/(__expf(2.f*x)+1.f); }

// coherence-point (MALL) access: sc0 sc1 bypasses L1/L2 — no fences needed
static __device__ __forceinline__ uint4 ld_cg16(const void* p){
  uint4 v;
  asm volatile("global_load_dwordx4 %0, %1, off sc0 sc1" : "=v"(v) : "v"(p) : "memory");
  return v;
}
static __device__ __forceinline__ unsigned ld_cg4(const void* p){
  unsigned v;
  asm volatile("global_load_dword %0, %1, off sc0 sc1\n\ts_waitcnt vmcnt(0)"
               : "=v"(v) : "v"(p) : "memory");
  return v;
}
static __device__ __forceinline__ void st_cg2(void* p, unsigned short s){
  unsigned v = s;
  asm volatile("global_store_short %0, %1, off sc0 sc1" :: "v"(p), "v"(v) : "memory");
}
static __device__ __forceinline__ void st_cg4(void* p, unsigned v){
  asm volatile("global_store_dword %0, %1, off sc0 sc1" :: "v"(p), "v"(v) : "memory");
}
static __device__ __forceinline__ void drain_vm(){
  asm volatile("s_waitcnt vmcnt(0)" ::: "memory");
}

// ---------------- prep kernels ----------------
__global__ void k_init(float* __restrict__ out, uint8_t* __restrict__ ws){
  int i = blockIdx.x*blockDim.x + threadIdx.x;
  int ns = gridDim.x*blockDim.x;
  uint32_t* z = (uint32_t*)(ws + OH0);
  const int n32 = (int)((OFLG + 16384u - OH0)/4u);   // rings + flags
  for (int k=i; k<n32; k+=ns) z[k] = 0u;
  for (int k=i; k<64*128; k+=ns) out[(size_t)(k>>7)*(512*128) + (k&127)] = 0.f;
}

__global__ void k_cvt(const float* __restrict__ x, const float* __restrict__ y,
                      uint8_t* __restrict__ ws){
  unsigned short* xb = (unsigned short*)(ws + OXBF);
  unsigned short* yb = (unsigned short*)(ws + OYBF);
  const int n = 64*512*128;
  int i = blockIdx.x*blockDim.x + threadIdx.x, ns = gridDim.x*blockDim.x;
  for (int k=i; k<n; k+=ns){ xb[k] = f2bf(x[k]); yb[k] = f2bf(y[k]); }
}

// gate-cell weight swizzle: frag idx = ((((ub*4 + w)*NKK + kk)*4 + g)*64 + lane)*8 + j
// mode 1 (cell0): k = kk==0 ? w*32+off : 128 + w*128 + (kk-1)*32 + off
// mode 0 (cell1): k = w*KC + kk*32 + off
__global__ void k_swzgate(const float* __restrict__ Wih, const float* __restrict__ Whh,
                          uint8_t* __restrict__ ws, size_t dstOff, int Kin, int KC, int NKK, int mode){
  unsigned short* dst = (unsigned short*)(ws + dstOff);
  const int total = 2048 * (KC*4);
  int i = blockIdx.x*blockDim.x + threadIdx.x, ns = gridDim.x*blockDim.x;
  for (int idx=i; idx<total; idx+=ns){
    int j = idx & 7;
    int lane = (idx >> 3) & 63;
    int t = idx >> 9;
    int g = t & 3; t >>= 2;
    int kk = t % NKK; t /= NKK;
    int w = t & 3; int ub = t >> 2;
    int off = ((lane>>4)<<3) + j;
    int k = mode ? (kk==0 ? w*32 + off : 128 + w*128 + (kk-1)*32 + off)
                 : (w*KC + kk*32 + off);
    int u = ub*16 + (lane&15);
    int row = g*512 + u;
    float v = (k < Kin) ? Wih[(size_t)row*Kin + k] : Whh[(size_t)row*512 + (k-Kin)];
    dst[idx] = f2bf(v);
  }
}

// clf weight swizzle: frag idx = (((wg*4 + w)*NKK + kk)*64 + lane)*8 + j ; k = w*Kw + kk*32 + off
__global__ void k_swzclf(const float* __restrict__ W, uint8_t* __restrict__ ws,
                         size_t dstOff, int nwgs, int Kw, int Ktot){
  unsigned short* dst = (unsigned short*)(ws + dstOff);
  const int NKK = Kw/32;
  const int total = nwgs*4*NKK*64*8;
  int i = blockIdx.x*blockDim.x + threadIdx.x, ns = gridDim.x*blockDim.x;
  for (int idx=i; idx<total; idx+=ns){
    int j = idx & 7;
    int lane = (idx >> 3) & 63;
    int t = idx >> 9;
    int kk = t % NKK; t /= NKK;
    int w = t & 3; int wg = t >> 2;
    int k = w*Kw + kk*32 + ((lane>>4)<<3) + j;
    int col = wg*16 + (lane&15);
    dst[idx] = f2bf(W[(size_t)col*Ktot + k]);
  }
}

// ---------------- persistent dataflow kernel ----------------
// roles: wg 0..63 cell0 (bt=wg>>5, ub=wg&31); 64..127 cell1; 128..143 hid; 144..151 log
__launch_bounds__(256, 1)
__global__ void k_seq(uint8_t* __restrict__ ws,
                      const float* __restrict__ eb0, const float* __restrict__ eb1,
                      const float* __restrict__ db0, const float* __restrict__ db1,
                      const float* __restrict__ cb1, const float* __restrict__ cb2,
                      float* __restrict__ out){
  __shared__ uint8_t smem[SMEM_BYTES];
  const int wg = blockIdx.x, tid = threadIdx.x;
  const int w = tid>>6, l = tid&63, lr = l&15, lg = l>>4;

  const unsigned short* xb = (const unsigned short*)(ws+OXBF);
  const unsigned short* yb = (const unsigned short*)(ws+OYBF);
  unsigned short* h0r = (unsigned short*)(ws+OH0);
  unsigned short* h1r = (unsigned short*)(ws+OH1);
  unsigned short* hpr = (unsigned short*)(ws+OHP);

  short8* BL = (short8*)smem;
  float*  P0 = (float*)(smem + 131072);   // padded partials: cell 32*68, clf 64*20
  float*  P1 = (float*)(smem + 139776);

  auto loadB = [&](size_t srcOff, int bytes){
    const uint4* s = (const uint4*)(ws + srcOff);
    uint4* d = (uint4*)smem;
    for (int i = tid; i < bytes/16; i += 256) d[i] = s[i];
  };
  auto pollge = [&](uint32_t baseOff, int n, int tgt, int tb){
    if (tgt > 0 && tid >= tb && tid < tb+n){
      const void* p = (const void*)(ws + baseOff + (size_t)(tid-tb)*64);
      while ((int)ld_cg4(p) < tgt) __builtin_amdgcn_s_sleep(2);
    }
  };
  auto setflag = [&](uint32_t slotOff, int val){
    drain_vm();        // each wave drains its OWN sc stores (asm stores are
    __syncthreads();   // invisible to the compiler's pre-barrier waitcnt)
    if (tid == 0) st_cg4(ws + slotOff, (unsigned)val);
  };

  if (wg < 128){
    // ---------------- LSTM cells ----------------
    const bool isC0 = wg < 64;
    const int cwg = isC0 ? wg : wg-64;
    const int bt = cwg>>5, ub = cwg&31;
    const int u = tid&15, ug = ub*16 + u;
    const int bbytes = isC0 ? 81920 : 131072;
    const uint32_t myflag = (isC0 ? OFC0 : OFC1) + (uint32_t)(bt*32+ub)*64u;

    float be[4], bd[4];
    {
      const float* e = isC0 ? eb0 : eb1;
      const float* d = isC0 ? db0 : db1;
      #pragma unroll
      for (int g=0; g<4; ++g){ be[g] = e[g*512+ug]; bd[g] = d[g*512+ug]; }
    }
    loadB((isC0 ? (size_t)OWE0 : (size_t)OWE1) + (size_t)ub*bbytes, bbytes);
    float cS0 = 0.f, cS1 = 0.f;
    __syncthreads();

    for (int t = 0; t < 1023; ++t){
      if (t == 512){
        __syncthreads();
        loadB((isC0 ? (size_t)OWD0 : (size_t)OWD1) + (size_t)ub*bbytes, bbytes);
      }
      if (isC0){
        pollge(OFC0 + bt*2048u, 32, t, 0);        // h0(t-1) ready (own group)
        pollge(OFC1 + bt*2048u, 32, t-7, 32);     // WAR: c1 done reading h0(t-8)
      } else {
        pollge(OFC0 + bt*2048u, 32, t+1, 0);      // h0(t) ready
        pollge(OFC1 + bt*2048u, 32, t, 32);       // h1(t-1) ready (own group)
        pollge(OFH, 16, t-519, 64);               // WAR: hid done reading h1(t-8)
      }
      __syncthreads();

      const int slotW = t&7, slotR = (t+7)&7;
      f32x4 acc[2][4];
      #pragma unroll
      for (int m=0;m<2;++m)
        #pragma unroll
        for (int g=0;g<4;++g) acc[m][g] = (f32x4){0.f,0.f,0.f,0.f};

      if (isC0){
        const unsigned short* xs = (t<512) ? xb : yb;
        const int tt = (t<512) ? t : t-512;
        short8 ax[2];
        uint4 ah[4][2];
        #pragma unroll
        for (int m=0;m<2;++m){
          const int b = bt*32 + m*16 + lr;
          ax[m] = *(const short8*)(xs + ((size_t)b*512 + tt)*128 + w*32 + (lg<<3));
          #pragma unroll
          for (int kk=1; kk<5; ++kk)
            ah[kk-1][m] = ld_cg16(h0r + ((size_t)slotR*64 + b)*512 + w*128 + (kk-1)*32 + (lg<<3));
        }
        drain_vm();
        __builtin_amdgcn_sched_barrier(0);
        #pragma unroll
        for (int g=0;g<4;++g){
          short8 bf = BL[((w*5+0)*4+g)*64 + l];
          acc[0][g] = __builtin_amdgcn_mfma_f32_16x16x32_bf16(ax[0], bf, acc[0][g],0,0,0);
          acc[1][g] = __builtin_amdgcn_mfma_f32_16x16x32_bf16(ax[1], bf, acc[1][g],0,0,0);
        }
        #pragma unroll
        for (int kk=1; kk<5; ++kk)
          #pragma unroll
          for (int g=0;g<4;++g){
            short8 bf = BL[((w*5+kk)*4+g)*64 + l];
            acc[0][g] = __builtin_amdgcn_mfma_f32_16x16x32_bf16(__builtin_bit_cast(short8, ah[kk-1][0]), bf, acc[0][g],0,0,0);
            acc[1][g] = __builtin_amdgcn_mfma_f32_16x16x32_bf16(__builtin_bit_cast(short8, ah[kk-1][1]), bf, acc[1][g],0,0,0);
          }
      } else {
        uint4 a[8][2];
        #pragma unroll
        for (int kk=0; kk<8; ++kk){
          const int k0 = w*256 + kk*32;
          #pragma unroll
          for (int m=0;m<2;++m){
            const int b = bt*32 + m*16 + lr;
            const void* ap = (k0 < 512)
              ? (const void*)(h0r + ((size_t)slotW*64 + b)*512 + k0 + (lg<<3))
              : (const void*)(h1r + ((size_t)slotR*64 + b)*512 + (k0-512) + (lg<<3));
            a[kk][m] = ld_cg16(ap);
          }
        }
        drain_vm();
        __builtin_amdgcn_sched_barrier(0);
        #pragma unroll
        for (int kk=0; kk<8; ++kk)
          #pragma unroll
          for (int g=0;g<4;++g){
            short8 bf = BL[((w*8+kk)*4+g)*64 + l];
            acc[0][g] = __builtin_amdgcn_mfma_f32_16x16x32_bf16(__builtin_bit_cast(short8, a[kk][0]), bf, acc[0][g],0,0,0);
            acc[1][g] = __builtin_amdgcn_mfma_f32_16x16x32_bf16(__builtin_bit_cast(short8, a[kk][1]), bf, acc[1][g],0,0,0);
          }
      }

      // 2-round split-K reduce: w0->P0, w1->P1; barrier; w2->P0+, w3->P1+
      {
        float* P = (w&1) ? P1 : P0;
        if (w < 2){
          #pragma unroll
          for (int m=0;m<2;++m)
            #pragma unroll
            for (int g=0;g<4;++g)
              #pragma unroll
              for (int r=0;r<4;++r)
                P[(m*16 + (lg<<2) + r)*68 + g*16 + lr] = acc[m][g][r];
        }
        __syncthreads();
        if (w >= 2){
          #pragma unroll
          for (int m=0;m<2;++m)
            #pragma unroll
            for (int g=0;g<4;++g)
              #pragma unroll
              for (int r=0;r<4;++r)
                P[(m*16 + (lg<<2) + r)*68 + g*16 + lr] += acc[m][g][r];
        }
        __syncthreads();
      }

      // activation epilogue: 2 outputs/thread (rows tid>>4 and +16, unit u)
      const float* bias = (t<512) ? be : bd;
      unsigned short* hout = isC0 ? h0r : h1r;
      #pragma unroll
      for (int s=0;s<2;++s){
        const int row = (tid>>4) + s*16;
        const int pi = row*68 + u;
        float gi = P0[pi]      + P1[pi]      + bias[0];
        float gf = P0[pi+16]   + P1[pi+16]   + bias[1];
        float gg = P0[pi+32]   + P1[pi+32]   + bias[2];
        float go = P0[pi+48]   + P1[pi+48]   + bias[3];
        float cprev = s ? cS1 : cS0;
        float c = sigm(gf)*cprev + sigm(gi)*tanh_(gg);
        if (s) cS1 = c; else cS0 = c;
        float h = sigm(go)*tanh_(c);
        st_cg2(hout + ((size_t)slotW*64 + (bt*32+row))*512 + ug, f2bf(h));
      }
      setflag(myflag, t+1);
    }
  } else if (wg < 144){
    // ---------------- clf hidden: relu(h1 @ W1^T + b1) ----------------
    const int hwg = wg - 128;
    const int u = tid&15, col = hwg*16 + u;
    const float bc = cb1[col];
    loadB((size_t)OWC1 + (size_t)hwg*16384, 16384);
    __syncthreads();
    for (int t2 = 0; t2 < 511; ++t2){
      pollge(OFC1, 64, 513+t2, 0);               // c1 (both halves) done step 512+t2
      pollge(OFL, 8, t2-7, 64);                  // WAR: log done reading hid(t2-8)
      __syncthreads();
      const int slot = (512+t2)&7, slw = t2&7;
      f32x4 ha[4];
      #pragma unroll
      for (int m=0;m<4;++m) ha[m] = (f32x4){0.f,0.f,0.f,0.f};
      uint4 a[4][4];
      #pragma unroll
      for (int kk=0; kk<4; ++kk)
        #pragma unroll
        for (int m=0;m<4;++m)
          a[kk][m] = ld_cg16(h1r + ((size_t)slot*64 + m*16+lr)*512 + w*128 + kk*32 + (lg<<3));
      drain_vm();
      __builtin_amdgcn_sched_barrier(0);
      #pragma unroll
      for (int kk=0; kk<4; ++kk){
        short8 bf = BL[(w*4+kk)*64 + l];
        #pragma unroll
        for (int m=0;m<4;++m)
          ha[m] = __builtin_amdgcn_mfma_f32_16x16x32_bf16(__builtin_bit_cast(short8, a[kk][m]), bf, ha[m],0,0,0);
      }
      {
        float* P = (w&1) ? P1 : P0;
        if (w < 2){
          #pragma unroll
          for (int m=0;m<4;++m)
            #pragma unroll
            for (int r=0;r<4;++r)
              P[(m*16 + (lg<<2) + r)*20 + lr] = ha[m][r];
        }
        __syncthreads();
        if (w >= 2){
          #pragma unroll
          for (int m=0;m<4;++m)
            #pragma unroll
            for (int r=0;r<4;++r)
              P[(m*16 + (lg<<2) + r)*20 + lr] += ha[m][r];
        }
        __syncthreads();
      }
      #pragma unroll
      for (int s=0;s<4;++s){
        const int row = (tid>>4) + s*16;
        float v = P0[row*20+u] + P1[row*20+u] + bc;
        v = fmaxf(v, 0.f);
        st_cg2(hpr + ((size_t)slw*64 + row)*256 + col, f2bf(v));
      }
      setflag(OFH + (uint32_t)hwg*64u, t2+1);
    }
  } else if (wg < 152){
    // ---------------- clf logits: hid @ W2^T + b2 -> out ----------------
    const int lwg = wg - 144;
    const int u = tid&15, col = lwg*16 + u;
    const float bc = cb2[col];
    loadB((size_t)OWC2 + (size_t)lwg*8192, 8192);
    __syncthreads();
    for (int t3 = 0; t3 < 511; ++t3){
      pollge(OFH, 16, t3+1, 0);
      __syncthreads();
      const int slot = t3&7;
      f32x4 la[4];
      #pragma unroll
      for (int m=0;m<4;++m) la[m] = (f32x4){0.f,0.f,0.f,0.f};
      uint4 a[2][4];
      #pragma unroll
      for (int kk=0; kk<2; ++kk)
        #pragma unroll
        for (int m=0;m<4;++m)
          a[kk][m] = ld_cg16(hpr + ((size_t)slot*64 + m*16+lr)*256 + w*64 + kk*32 + (lg<<3));
      drain_vm();
      __builtin_amdgcn_sched_barrier(0);
      #pragma unroll
      for (int kk=0; kk<2; ++kk){
        short8 bf = BL[(w*2+kk)*64 + l];
        #pragma unroll
        for (int m=0;m<4;++m)
          la[m] = __builtin_amdgcn_mfma_f32_16x16x32_bf16(__builtin_bit_cast(short8, a[kk][m]), bf, la[m],0,0,0);
      }
      {
        float* P = (w&1) ? P1 : P0;
        if (w < 2){
          #pragma unroll
          for (int m=0;m<4;++m)
            #pragma unroll
            for (int r=0;r<4;++r)
              P[(m*16 + (lg<<2) + r)*20 + lr] = la[m][r];
        }
        __syncthreads();
        if (w >= 2){
          #pragma unroll
          for (int m=0;m<4;++m)
            #pragma unroll
            for (int r=0;r<4;++r)
              P[(m*16 + (lg<<2) + r)*20 + lr] += la[m][r];
        }
        __syncthreads();
      }
      #pragma unroll
      for (int s=0;s<4;++s){
        const int row = (tid>>4) + s*16;
        float v = P0[row*20+u] + P1[row*20+u] + bc;
        out[((size_t)row*512 + (t3+1))*128 + col] = v;
      }
      setflag(OFL + (uint32_t)lwg*64u, t3+1);
    }
  }
}

// ---------------- launch ----------------
extern "C" void kernel_launch(void* const* d_in, const int* in_sizes, int n_in,
                              void* d_out, int out_size, void* d_ws, size_t ws_size,
                              hipStream_t stream){
  const float* x   = (const float*)d_in[0];
  const float* y   = (const float*)d_in[1];
  const float* eW0 = (const float*)d_in[2];
  const float* eU0 = (const float*)d_in[3];
  const float* eb0 = (const float*)d_in[4];
  const float* eW1 = (const float*)d_in[5];
  const float* eU1 = (const float*)d_in[6];
  const float* eb1 = (const float*)d_in[7];
  const float* dW0 = (const float*)d_in[8];
  const float* dU0 = (const float*)d_in[9];
  const float* db0 = (const float*)d_in[10];
  const float* dW1 = (const float*)d_in[11];
  const float* dU1 = (const float*)d_in[12];
  const float* db1 = (const float*)d_in[13];
  const float* cW1 = (const float*)d_in[14];
  const float* cb1 = (const float*)d_in[15];
  const float* cW2 = (const float*)d_in[16];
  const float* cb2 = (const float*)d_in[17];
  float* out = (float*)d_out;
  uint8_t* ws = (uint8_t*)d_ws;
  (void)in_sizes; (void)n_in; (void)out_size; (void)ws_size;

  k_init<<<dim3(256), dim3(256), 0, stream>>>(out, ws);
  k_cvt<<<dim3(2048), dim3(256), 0, stream>>>(x, y, ws);
  k_swzgate<<<dim3(1280), dim3(256), 0, stream>>>(eW0, eU0, ws, (size_t)OWE0, 128, 160, 5, 1);
  k_swzgate<<<dim3(1280), dim3(256), 0, stream>>>(dW0, dU0, ws, (size_t)OWD0, 128, 160, 5, 1);
  k_swzgate<<<dim3(2048), dim3(256), 0, stream>>>(eW1, eU1, ws, (size_t)OWE1, 512, 256, 8, 0);
  k_swzgate<<<dim3(2048), dim3(256), 0, stream>>>(dW1, dU1, ws, (size_t)OWD1, 512, 256, 8, 0);
  k_swzclf<<<dim3(256), dim3(256), 0, stream>>>(cW1, ws, (size_t)OWC1, 16, 128, 512);
  k_swzclf<<<dim3(64),  dim3(256), 0, stream>>>(cW2, ws, (size_t)OWC2, 8, 64, 256);
  k_seq<<<dim3(152), dim3(256), 0, stream>>>(ws, eb0, eb1, db0, db1, cb1, cb2, out);
}